// Round 1
// baseline (520.551 us; speedup 1.0000x reference)
//
#include <hip/hip_runtime.h>
#include <hip/hip_bf16.h>

typedef _Float16 half8 __attribute__((ext_vector_type(8)));
typedef float floatx4 __attribute__((ext_vector_type(4)));

#define B_ 4
#define C_ 256
#define N_ 4096
#define JS 8            // j-range splits per row
#define BM 128
#define BN 128
#define BK 32
#define JRANGE (N_ / JS)      // 512
#define JTILES (JRANGE / BN)  // 4

// workspace offsets (bytes)
#define OFF_FN   ((size_t)0)          // 4*4096*256 fp16 = 8 MB
#define OFF_PROB ((size_t)8388608)    // 16384 fp32     = 64 KB
#define OFF_PV   ((size_t)8454144)    // 16384*64 fp32  = 4 MB
#define OFF_PI   ((size_t)12648448)   // 16384*64 int32 = 4 MB

#define LDA 40   // LDS halfs per A/B row (32 + 8 pad -> 80B rows, 16B aligned, 2-way banks = free)
#define LDC 36   // LDS floats per C-slice row (32 + 4 pad)

__device__ __forceinline__ void topk8_insert(float v, int j, float tv[8], int tj[8], float& tmin) {
    if (v > tmin) {
        bool done = false;
#pragma unroll
        for (int s = 0; s < 8; ++s) {
            bool take = (!done) && (tv[s] == tmin);
            if (take) { tv[s] = v; tj[s] = j; }
            done = done || take;
        }
        float nm = tv[0];
#pragma unroll
        for (int s = 1; s < 8; ++s) nm = fminf(nm, tv[s]);
        tmin = nm;
    }
}

// ---------------- Kernel 1: norms + fp16 transpose-convert + sigmoid ----------------
__global__ __launch_bounds__(256) void prep_kernel(const float* __restrict__ feats,
                                                   const float* __restrict__ logits,
                                                   _Float16* __restrict__ fn,
                                                   float* __restrict__ prob,
                                                   float* __restrict__ out) {
    int gid = blockIdx.x * 256 + threadIdx.x;       // 0..16383 = (b, i)
    if (gid == 0) out[0] = 0.f;                     // zero the loss accumulator
    int b = gid >> 12, i = gid & (N_ - 1);
    const float* fb = feats + (size_t)b * C_ * N_ + i;
    float ss = 0.f;
#pragma unroll 8
    for (int c = 0; c < C_; ++c) { float v = fb[(size_t)c * N_]; ss += v * v; }
    float inv = 1.f / fmaxf(sqrtf(ss), 1e-12f);
    _Float16* fr = fn + (size_t)(b * N_ + i) * C_;  // row-major n x c (NT layout for gram)
#pragma unroll 8
    for (int c = 0; c < C_; ++c) fr[c] = (_Float16)(fb[(size_t)c * N_] * inv);
    float lg = logits[b * N_ + i];
    prob[b * N_ + i] = 1.f / (1.f + expf(-lg));
}

// ---------------- Kernel 2: tiled MFMA gram + streaming per-row top-8 ----------------
__global__ __launch_bounds__(256) void gram_topk_kernel(const _Float16* __restrict__ fn,
                                                        float* __restrict__ pv,
                                                        int* __restrict__ pi) {
    __shared__ __align__(16) char smem[2 * 10240 + BM * LDC * 4];
    _Float16* As = (_Float16*)smem;             // BM x BK, stride LDA
    _Float16* Bs = (_Float16*)(smem + 10240);   // BN x BK, stride LDA
    float*    Cs = (float*)(smem + 20480);      // BM x 32 slice, stride LDC
    float*    mv = (float*)smem;                // overlay: final merge vals (8KB)
    int*      mi = (int*)(smem + 10240);        // overlay: final merge idx  (8KB)

    const int t    = threadIdx.x;
    const int lane = t & 63;
    const int w    = t >> 6;        // wave 0..3 -> rows w*32..w*32+31
    const int m16  = lane & 15;
    const int q    = lane >> 4;     // quad

    const int bid = blockIdx.x;
    const int js  = bid & (JS - 1);
    const int it  = (bid >> 3) & 31;
    const int b   = bid >> 8;

    const int i0 = it * BM;
    const _Float16* fnb = fn + (size_t)b * N_ * C_;

    float tv[8]; int tj[8]; float tmin = -__builtin_inff();
#pragma unroll
    for (int s = 0; s < 8; ++s) { tv[s] = -__builtin_inff(); tj[s] = 0; }

    for (int jtile = 0; jtile < JTILES; ++jtile) {
        const int j0 = js * JRANGE + jtile * BN;
        floatx4 acc[2][8];
#pragma unroll
        for (int ri = 0; ri < 2; ++ri)
#pragma unroll
            for (int jj = 0; jj < 8; ++jj) acc[ri][jj] = floatx4{0.f, 0.f, 0.f, 0.f};

        for (int kc = 0; kc < 8; ++kc) {
            // stage A and B K-chunks: 512 x 16B chunks each, 2 per thread, coalesced
#pragma unroll
            for (int r = 0; r < 2; ++r) {
                int ch = t + r * 256;
                int row = ch >> 2, c = ch & 3;
                float4 da = *(const float4*)(fnb + (size_t)(i0 + row) * C_ + kc * BK + c * 8);
                float4 db = *(const float4*)(fnb + (size_t)(j0 + row) * C_ + kc * BK + c * 8);
                *(float4*)&As[row * LDA + c * 8] = da;
                *(float4*)&Bs[row * LDA + c * 8] = db;
            }
            __syncthreads();
            // A-frag: lane holds A[m=lane&15][k=q*8..q*8+7]  (16B contiguous)
            half8 a0 = *(const half8*)&As[(w * 32 + m16) * LDA + q * 8];
            half8 a1 = *(const half8*)&As[(w * 32 + 16 + m16) * LDA + q * 8];
#pragma unroll
            for (int jj = 0; jj < 8; ++jj) {
                half8 bf = *(const half8*)&Bs[(jj * 16 + m16) * LDA + q * 8];
                acc[0][jj] = __builtin_amdgcn_mfma_f32_16x16x32_f16(a0, bf, acc[0][jj], 0, 0, 0);
                acc[1][jj] = __builtin_amdgcn_mfma_f32_16x16x32_f16(a1, bf, acc[1][jj], 0, 0, 0);
            }
            __syncthreads();
        }

        // scan C in 4 slices of 32 cols; C/D layout: col=lane&15, row=q*4+reg
        for (int s4 = 0; s4 < 4; ++s4) {
#pragma unroll
            for (int jh = 0; jh < 2; ++jh) {
                int jj = s4 * 2 + jh;
#pragma unroll
                for (int ri = 0; ri < 2; ++ri)
#pragma unroll
                    for (int r = 0; r < 4; ++r) {
                        int row = w * 32 + ri * 16 + q * 4 + r;
                        Cs[row * LDC + jh * 16 + m16] = acc[ri][jj][r];
                    }
            }
            __syncthreads();
            {
                int row = t >> 1;
                const float* cr = &Cs[row * LDC + (t & 1) * 16];
                int jb = j0 + s4 * 32 + (t & 1) * 16;
#pragma unroll
                for (int k2 = 0; k2 < 16; ++k2) topk8_insert(cr[k2], jb + k2, tv, tj, tmin);
            }
            __syncthreads();
        }
    }

    // block-end merge: 2 threads per row -> one partial top-8 per (row, js)
#pragma unroll
    for (int s = 0; s < 8; ++s) { mv[t * 8 + s] = tv[s]; mi[t * 8 + s] = tj[s]; }
    __syncthreads();
    if (t < BM) {
        float fv[8]; int fj[8]; float fm = -__builtin_inff();
#pragma unroll
        for (int s = 0; s < 8; ++s) { fv[s] = -__builtin_inff(); fj[s] = 0; }
#pragma unroll
        for (int src = 0; src < 2; ++src) {
            int base = (t * 2 + src) * 8;
#pragma unroll
            for (int s = 0; s < 8; ++s) topk8_insert(mv[base + s], mi[base + s], fv, fj, fm);
        }
        size_t rowg = (size_t)b * N_ + i0 + t;
#pragma unroll
        for (int s = 0; s < 8; ++s) {
            pv[(rowg * JS + js) * 8 + s] = fv[s];
            pi[(rowg * JS + js) * 8 + s] = fj[s];
        }
    }
}

// ---------------- Kernel 3: merge partials, gather prob, reduce loss ----------------
__global__ __launch_bounds__(256) void merge_loss_kernel(const float* __restrict__ pv,
                                                         const int* __restrict__ pi,
                                                         const float* __restrict__ prob,
                                                         float* __restrict__ out) {
    __shared__ float red[256];
    int row = blockIdx.x * 256 + threadIdx.x;   // 0..16383
    int b = row >> 12;
    float tv[8]; int tj[8]; float tmin = -__builtin_inff();
#pragma unroll
    for (int s = 0; s < 8; ++s) { tv[s] = -__builtin_inff(); tj[s] = 0; }
    const float* v = pv + (size_t)row * (JS * 8);
    const int*   j = pi + (size_t)row * (JS * 8);
    for (int k = 0; k < JS * 8; ++k) topk8_insert(v[k], j[k], tv, tj, tmin);
    float p = prob[row];
    const float* pb = prob + b * N_;
    float s = 0.f;
#pragma unroll
    for (int k = 0; k < 8; ++k) s += fabsf(p - pb[tj[k]]);
    red[threadIdx.x] = s;
    __syncthreads();
    for (int off = 128; off > 0; off >>= 1) {
        if (threadIdx.x < off) red[threadIdx.x] += red[threadIdx.x + off];
        __syncthreads();
    }
    if (threadIdx.x == 0) atomicAdd(out, red[0] * (1.f / (B_ * N_ * 8.0f)));
}

extern "C" void kernel_launch(void* const* d_in, const int* in_sizes, int n_in,
                              void* d_out, int out_size, void* d_ws, size_t ws_size,
                              hipStream_t stream) {
    const float* feats  = (const float*)d_in[0];
    const float* logits = (const float*)d_in[1];
    float* out = (float*)d_out;
    char* ws = (char*)d_ws;
    _Float16* fn  = (_Float16*)(ws + OFF_FN);
    float* prob   = (float*)(ws + OFF_PROB);
    float* pv     = (float*)(ws + OFF_PV);
    int*   pi     = (int*)(ws + OFF_PI);

    prep_kernel<<<64, 256, 0, stream>>>(feats, logits, fn, prob, out);
    gram_topk_kernel<<<B_ * 32 * JS, 256, 0, stream>>>(fn, pv, pi);
    merge_loss_kernel<<<64, 256, 0, stream>>>(pv, pi, prob, out);
}

// Round 2
// 274.447 us; speedup vs baseline: 1.8967x; 1.8967x over previous
//
#include <hip/hip_runtime.h>
#include <hip/hip_bf16.h>

typedef _Float16 half8 __attribute__((ext_vector_type(8)));
typedef float floatx4 __attribute__((ext_vector_type(4)));

#define B_ 4
#define C_ 256
#define N_ 4096
#define JS 8            // j-range splits per row
#define BM 128
#define BN 128
#define BK 32
#define JRANGE (N_ / JS)      // 512
#define JTILES (JRANGE / BN)  // 4

// workspace offsets (bytes)
#define OFF_FN   ((size_t)0)          // 4*4096*256 fp16 = 8 MB
#define OFF_PROB ((size_t)8388608)    // 16384 fp32     = 64 KB
#define OFF_PV   ((size_t)8454144)    // 16384*64 fp32  = 4 MB (also reused as inv[16384] before gram runs)
#define OFF_PI   ((size_t)12648448)   // 16384*64 int32 = 4 MB

#define LDA 40   // LDS halfs per A/B row (32 + 8 pad -> 80B rows, 16B aligned, 2-way banks = free)
#define LDC 33   // LDS floats per C-slice row: stride ≡ 1 mod 32 → scan is exactly 2-way (free)

__device__ __forceinline__ void topk8_insert(float v, int j, float tv[8], int tj[8], float& tmin) {
    if (v > tmin) {
        bool done = false;
#pragma unroll
        for (int s = 0; s < 8; ++s) {
            bool take = (!done) && (tv[s] == tmin);
            if (take) { tv[s] = v; tj[s] = j; }
            done = done || take;
        }
        float nm = tv[0];
#pragma unroll
        for (int s = 1; s < 8; ++s) nm = fminf(nm, tv[s]);
        tmin = nm;
    }
}

// ---------------- Kernel 1a: row norms + sigmoid ----------------
__global__ __launch_bounds__(256) void norm_kernel(const float* __restrict__ feats,
                                                   const float* __restrict__ logits,
                                                   float* __restrict__ inv,
                                                   float* __restrict__ prob,
                                                   float* __restrict__ out) {
    int gid = blockIdx.x * 256 + threadIdx.x;       // 0..16383 = (b, i)
    if (gid == 0) out[0] = 0.f;                     // zero the loss accumulator
    int b = gid >> 12, i = gid & (N_ - 1);
    const float* fb = feats + (size_t)b * C_ * N_ + i;
    float ss = 0.f;
#pragma unroll 8
    for (int c = 0; c < C_; ++c) { float v = fb[(size_t)c * N_]; ss += v * v; }
    inv[gid] = 1.f / fmaxf(sqrtf(ss), 1e-12f);
    float lg = logits[gid];
    prob[gid] = 1.f / (1.f + expf(-lg));
}

// ---------------- Kernel 1b: transpose-convert to fp16 n x c rows ----------------
// one thread -> 8 channels of one row -> single 16B coalesced store
__global__ __launch_bounds__(256) void convert_kernel(const float* __restrict__ feats,
                                                      const float* __restrict__ inv,
                                                      _Float16* __restrict__ fn) {
    int g = blockIdx.x * 256 + threadIdx.x;        // 0..524287
    int row = g >> 5;                              // b*4096 + i
    int c0 = (g & 31) * 8;
    int b = row >> 12, i = row & (N_ - 1);
    const float* fb = feats + (size_t)b * C_ * N_ + (size_t)c0 * N_ + i;
    float s = inv[row];
    half8 h;
#pragma unroll
    for (int j = 0; j < 8; ++j) h[j] = (_Float16)(fb[(size_t)j * N_] * s);
    *(half8*)(fn + (size_t)row * C_ + c0) = h;
}

// ---------------- Kernel 2: tiled MFMA gram + streaming per-row top-8 ----------------
__global__ __launch_bounds__(256) void gram_topk_kernel(const _Float16* __restrict__ fn,
                                                        float* __restrict__ pv,
                                                        int* __restrict__ pi) {
    __shared__ __align__(16) char smem[2 * 10240 + BM * LDC * 4];
    _Float16* As = (_Float16*)smem;             // BM x BK, stride LDA
    _Float16* Bs = (_Float16*)(smem + 10240);   // BN x BK, stride LDA
    float*    Cs = (float*)(smem + 20480);      // BM x 32 slice, stride LDC
    float*    mv = (float*)smem;                // overlay: final merge vals (8KB)
    int*      mi = (int*)(smem + 10240);        // overlay: final merge idx  (8KB)

    const int t    = threadIdx.x;
    const int lane = t & 63;
    const int w    = t >> 6;        // wave 0..3 -> rows w*32..w*32+31
    const int m16  = lane & 15;
    const int q    = lane >> 4;     // quad

    const int bid = blockIdx.x;
    const int js  = bid & (JS - 1);
    const int it  = (bid >> 3) & 31;
    const int b   = bid >> 8;

    const int i0 = it * BM;
    const _Float16* fnb = fn + (size_t)b * N_ * C_;

    float tv[8]; int tj[8]; float tmin = -__builtin_inff();
#pragma unroll
    for (int s = 0; s < 8; ++s) { tv[s] = -__builtin_inff(); tj[s] = 0; }

    for (int jtile = 0; jtile < JTILES; ++jtile) {
        const int j0 = js * JRANGE + jtile * BN;
        floatx4 acc[2][8];
#pragma unroll
        for (int ri = 0; ri < 2; ++ri)
#pragma unroll
            for (int jj = 0; jj < 8; ++jj) acc[ri][jj] = floatx4{0.f, 0.f, 0.f, 0.f};

        for (int kc = 0; kc < 8; ++kc) {
            // stage A and B K-chunks: 512 x 16B chunks each, 2 per thread, coalesced
#pragma unroll
            for (int r = 0; r < 2; ++r) {
                int ch = t + r * 256;
                int row = ch >> 2, c = ch & 3;
                float4 da = *(const float4*)(fnb + (size_t)(i0 + row) * C_ + kc * BK + c * 8);
                float4 db = *(const float4*)(fnb + (size_t)(j0 + row) * C_ + kc * BK + c * 8);
                *(float4*)&As[row * LDA + c * 8] = da;
                *(float4*)&Bs[row * LDA + c * 8] = db;
            }
            __syncthreads();
            // A-frag: lane holds A[m=lane&15][k=q*8..q*8+7]  (16B contiguous)
            half8 a0 = *(const half8*)&As[(w * 32 + m16) * LDA + q * 8];
            half8 a1 = *(const half8*)&As[(w * 32 + 16 + m16) * LDA + q * 8];
#pragma unroll
            for (int jj = 0; jj < 8; ++jj) {
                half8 bf = *(const half8*)&Bs[(jj * 16 + m16) * LDA + q * 8];
                acc[0][jj] = __builtin_amdgcn_mfma_f32_16x16x32_f16(a0, bf, acc[0][jj], 0, 0, 0);
                acc[1][jj] = __builtin_amdgcn_mfma_f32_16x16x32_f16(a1, bf, acc[1][jj], 0, 0, 0);
            }
            __syncthreads();
        }

        // scan C in 4 slices of 32 cols; C/D layout: col=lane&15, row=q*4+reg
        // s4/jh fully unrolled -> acc indices are compile-time (keeps acc in registers!)
#pragma unroll
        for (int s4 = 0; s4 < 4; ++s4) {
#pragma unroll
            for (int jh = 0; jh < 2; ++jh) {
                const int jj = s4 * 2 + jh;
#pragma unroll
                for (int ri = 0; ri < 2; ++ri)
#pragma unroll
                    for (int r = 0; r < 4; ++r) {
                        int row = w * 32 + ri * 16 + q * 4 + r;
                        Cs[row * LDC + jh * 16 + m16] = acc[ri][jj][r];
                    }
            }
            __syncthreads();
            {
                int row = t >> 1;
                const float* cr = &Cs[row * LDC + (t & 1) * 16];
                int jb = j0 + s4 * 32 + (t & 1) * 16;
#pragma unroll
                for (int k2 = 0; k2 < 16; ++k2) topk8_insert(cr[k2], jb + k2, tv, tj, tmin);
            }
            __syncthreads();
        }
    }

    // block-end merge: 2 threads per row -> one partial top-8 per (row, js)
#pragma unroll
    for (int s = 0; s < 8; ++s) { mv[t * 8 + s] = tv[s]; mi[t * 8 + s] = tj[s]; }
    __syncthreads();
    if (t < BM) {
        float fv[8]; int fj[8]; float fm = -__builtin_inff();
#pragma unroll
        for (int s = 0; s < 8; ++s) { fv[s] = -__builtin_inff(); fj[s] = 0; }
#pragma unroll
        for (int src = 0; src < 2; ++src) {
            int base = (t * 2 + src) * 8;
#pragma unroll
            for (int s = 0; s < 8; ++s) topk8_insert(mv[base + s], mi[base + s], fv, fj, fm);
        }
        size_t rowg = (size_t)b * N_ + i0 + t;
#pragma unroll
        for (int s = 0; s < 8; ++s) {
            pv[(rowg * JS + js) * 8 + s] = fv[s];
            pi[(rowg * JS + js) * 8 + s] = fj[s];
        }
    }
}

// ---------------- Kernel 3: merge partials, gather prob, reduce loss ----------------
__global__ __launch_bounds__(256) void merge_loss_kernel(const float* __restrict__ pv,
                                                         const int* __restrict__ pi,
                                                         const float* __restrict__ prob,
                                                         float* __restrict__ out) {
    __shared__ float red[256];
    int row = blockIdx.x * 256 + threadIdx.x;   // 0..16383
    int b = row >> 12;
    float tv[8]; int tj[8]; float tmin = -__builtin_inff();
#pragma unroll
    for (int s = 0; s < 8; ++s) { tv[s] = -__builtin_inff(); tj[s] = 0; }
    const float* v = pv + (size_t)row * (JS * 8);
    const int*   j = pi + (size_t)row * (JS * 8);
    for (int k = 0; k < JS * 8; ++k) topk8_insert(v[k], j[k], tv, tj, tmin);
    float p = prob[row];
    const float* pb = prob + b * N_;
    float s = 0.f;
#pragma unroll
    for (int k = 0; k < 8; ++k) s += fabsf(p - pb[tj[k]]);
    red[threadIdx.x] = s;
    __syncthreads();
    for (int off = 128; off > 0; off >>= 1) {
        if (threadIdx.x < off) red[threadIdx.x] += red[threadIdx.x + off];
        __syncthreads();
    }
    if (threadIdx.x == 0) atomicAdd(out, red[0] * (1.f / (B_ * N_ * 8.0f)));
}

extern "C" void kernel_launch(void* const* d_in, const int* in_sizes, int n_in,
                              void* d_out, int out_size, void* d_ws, size_t ws_size,
                              hipStream_t stream) {
    const float* feats  = (const float*)d_in[0];
    const float* logits = (const float*)d_in[1];
    float* out = (float*)d_out;
    char* ws = (char*)d_ws;
    _Float16* fn  = (_Float16*)(ws + OFF_FN);
    float* prob   = (float*)(ws + OFF_PROB);
    float* pv     = (float*)(ws + OFF_PV);
    int*   pi     = (int*)(ws + OFF_PI);
    float* inv    = (float*)(ws + OFF_PV);   // reused: inv consumed by convert_kernel before gram writes pv

    norm_kernel<<<64, 256, 0, stream>>>(feats, logits, inv, prob, out);
    convert_kernel<<<2048, 256, 0, stream>>>(feats, inv, fn);
    gram_topk_kernel<<<B_ * 32 * JS, 256, 0, stream>>>(fn, pv, pi);
    merge_loss_kernel<<<64, 256, 0, stream>>>(pv, pi, prob, out);
}